// Round 17
// baseline (66.547 us; speedup 1.0000x reference)
//
#include <hip/hip_runtime.h>
#include <stdint.h>

typedef _Float16 f16x2 __attribute__((ext_vector_type(2)));
typedef _Float16 f16x4 __attribute__((ext_vector_type(4)));
typedef _Float16 f16x8 __attribute__((ext_vector_type(8)));
typedef __fp16   hf16x2 __attribute__((ext_vector_type(2)));
typedef float    f32x4 __attribute__((ext_vector_type(4)));
typedef uint4    u128a __attribute__((may_alias));

union HU   { uint32_t u; _Float16 h[2]; };
union B128 { uint4 q; f16x8 v; };
union PK2  { hf16x2 a; f16x2 b; };

__device__ __forceinline__ f16x2 pkrtz2(float lo, float hi) {
  PK2 u; u.a = __builtin_amdgcn_cvt_pkrtz(lo, hi);
  return u.b;
}

__device__ __forceinline__ f16x8 cat4(f16x2 a, f16x2 b, f16x2 c, f16x2 d) {
  f16x4 ab = __builtin_shufflevector(a, b, 0, 1, 2, 3);
  f16x4 cd = __builtin_shufflevector(c, d, 0, 1, 2, 3);
  return __builtin_shufflevector(ab, cd, 0, 1, 2, 3, 4, 5, 6, 7);
}

__device__ __forceinline__ float fast_exp2(float x) {
#if __has_builtin(__builtin_amdgcn_exp2f)
  return __builtin_amdgcn_exp2f(x);
#else
  return exp2f(x);
#endif
}
__device__ __forceinline__ float fast_rcp(float x) {
#if __has_builtin(__builtin_amdgcn_rcpf)
  return __builtin_amdgcn_rcpf(x);
#else
  return 1.0f / x;
#endif
}

// Degree-4 Taylor jet of tanh (general).
__device__ __forceinline__ void tanh_jets(float u0, float u1, float u2, float u3, float u4,
                                          float& t0, float& t1, float& t2, float& t3, float& t4) {
  float aa = fminf(fmaf(2.8853900817779268f, u0, 2.0f), 127.0f);
  float e4 = fast_exp2(aa);                    // 4·e^{2u0}
  float r  = fast_rcp(fmaf(0.25f, e4, 1.0f));  // 1/(e+1)
  t0 = fmaf(-2.0f, r, 1.0f);                   // tanh(u0)
  float v0 = e4 * (r * r);                     // sech²(u0)
  t1 = v0 * u1;
  float h1 = t0 * t1;                          // v1 = -2·h1
  t2 = fmaf(u2, v0, -(u1 * h1));
  float v2 = -fmaf(t0 + t0, t2, t1 * t1);
  t3 = fmaf(u3, v0, fmaf(-1.3333333333f * u2, h1, 0.3333333333f * u1 * v2));
  float v3 = -2.0f * fmaf(t0, t3, t1 * t2);
  t4 = fmaf(u4, v0, fmaf(-1.5f * u3, h1, fmaf(0.5f * u2, v2, 0.25f * u1 * v3)));
}

// Specialized for layer 1: u2 = u3 = u4 = 0.
__device__ __forceinline__ void tanh_jets1(float u0, float u1,
                                           float& t0, float& t1, float& t2, float& t3, float& t4) {
  float aa = fminf(fmaf(2.8853900817779268f, u0, 2.0f), 127.0f);
  float e4 = fast_exp2(aa);
  float r  = fast_rcp(fmaf(0.25f, e4, 1.0f));
  t0 = fmaf(-2.0f, r, 1.0f);
  float v0 = e4 * (r * r);
  t1 = v0 * u1;
  float h1 = t0 * t1;
  t2 = -(u1 * h1);
  float v2 = -fmaf(t0 + t0, t2, t1 * t1);
  t3 = 0.3333333333f * (u1 * v2);
  float v3 = -2.0f * fmaf(t0, t3, t1 * t2);
  t4 = 0.25f * (u1 * v3);
}

// ws layout (dwords) — identical to R6/R11:
//   [0    .. 511 ]  P1: [h][8] floats = {W1[0][h],W1[1][h],W1[2][h],W1[3][h],b1[h],0,0,0}
//   [512  .. 2559]  W2 A-frags, k2(g,j,s) = 16g + 8s + j          (frag fi = tm*2+s)
//   [2560 .. 4607]  W3 A-frags, k3(g,j,s) = 32s + 16*(j>>2) + 4g + (j&3)
//   [4608 .. 4671]  W4 as plain f32[64]
__global__ void prep_kernel(const float* __restrict__ W1, const float* __restrict__ b1,
                            const float* __restrict__ W2, const float* __restrict__ W3,
                            const float* __restrict__ W4, uint32_t* __restrict__ ws) {
  const int t = threadIdx.x;  // 256 threads, 1 block
  float* P1 = (float*)ws;
  if (t < 64) {
    P1[t * 8 + 0] = W1[0 * 64 + t];
    P1[t * 8 + 1] = W1[1 * 64 + t];
    P1[t * 8 + 2] = W1[2 * 64 + t];
    P1[t * 8 + 3] = W1[3 * 64 + t];
    P1[t * 8 + 4] = b1[t];
    P1[t * 8 + 5] = 0.f; P1[t * 8 + 6] = 0.f; P1[t * 8 + 7] = 0.f;
  }
  for (int idx = t; idx < 2048; idx += 256) {
    const int fi = idx >> 8;            // frag index 0..7 = tm*2 + s
    const int tm = fi >> 1, s = fi & 1;
    const int l  = (idx >> 2) & 63;     // lane
    const int pj = idx & 3;             // dword: halves j0=2pj, j0+1
    const int g  = l >> 4;
    const int mm = 16 * tm + (l & 15);  // h_out row
    const int j0 = 2 * pj, j1 = 2 * pj + 1;
    const int k2a = 16 * g + 8 * s + j0;
    const int k2b = 16 * g + 8 * s + j1;
    HU a; a.h[0] = (_Float16)W2[k2a * 64 + mm]; a.h[1] = (_Float16)W2[k2b * 64 + mm];
    ws[512 + idx] = a.u;
    const int k3a = 32 * s + 16 * (j0 >> 2) + 4 * g + (j0 & 3);
    const int k3b = 32 * s + 16 * (j1 >> 2) + 4 * g + (j1 & 3);
    HU b; b.h[0] = (_Float16)W3[k3a * 64 + mm]; b.h[1] = (_Float16)W3[k3b * 64 + mm];
    ws[2560 + idx] = b.u;
  }
  if (t < 64) {
    ws[4608 + t] = __float_as_uint(W4[t]);
  }
}

#define MFMA16(A, B, C) __builtin_amdgcn_mfma_f32_16x16x32_f16((A), (B), (C), 0, 0, 0)

// One A-frag vs all 5 jet B-frags of half S, accumulating into half-tile T (0/1).
#define MM5H(AF, T, S, BF) { \
    acc[0][T] = MFMA16((AF).v, BF[0][S], acc[0][T]); \
    acc[1][T] = MFMA16((AF).v, BF[1][S], acc[1][T]); \
    acc[2][T] = MFMA16((AF).v, BF[2][S], acc[2][T]); \
    acc[3][T] = MFMA16((AF).v, BF[3][S], acc[3][T]); \
    acc[4][T] = MFMA16((AF).v, BF[4][S], acc[4][T]); }

// init the 2 half-tile accumulators with bias tiles (2*HH, 2*HH+1)
#define INIT2(BIAS, HH) { \
  const float4 bv0_ = *(const float4*)((BIAS) + 16 * (2 * (HH) + 0) + 4 * g); \
  const float4 bv1_ = *(const float4*)((BIAS) + 16 * (2 * (HH) + 1) + 4 * g); \
  acc[0][0] = (f32x4){bv0_.x, bv0_.y, bv0_.z, bv0_.w}; \
  acc[0][1] = (f32x4){bv1_.x, bv1_.y, bv1_.z, bv1_.w}; \
  acc[1][0] = (f32x4){0.f, 0.f, 0.f, 0.f}; acc[1][1] = (f32x4){0.f, 0.f, 0.f, 0.f}; \
  acc[2][0] = (f32x4){0.f, 0.f, 0.f, 0.f}; acc[2][1] = (f32x4){0.f, 0.f, 0.f, 0.f}; \
  acc[3][0] = (f32x4){0.f, 0.f, 0.f, 0.f}; acc[3][1] = (f32x4){0.f, 0.f, 0.f, 0.f}; \
  acc[4][0] = (f32x4){0.f, 0.f, 0.f, 0.f}; acc[4][1] = (f32x4){0.f, 0.f, 0.f, 0.f}; }

// L1: pair (h0, h0+1) of half S, pair-index DI -> 5 packed dwords (named outs)
#define L1P(S, DI, D0, D1, D2, D3, D4) { \
  const int h0_ = 16 * g + 8 * (S) + 2 * (DI); \
  float A0_, A1_, A2_, A3_, A4_, B0_, B1_, B2_, B3_, B4_; \
  { const float4 wv_ = *(const float4*)(P1f + h0_ * 8); \
    const float bb_  = P1f[h0_ * 8 + 4]; \
    float u0_ = fmaf(wv_.x, x, fmaf(wv_.y, f1, fmaf(wv_.z, f2, fmaf(wv_.w, f3, bb_)))); \
    tanh_jets1(u0_, wv_.x, A0_, A1_, A2_, A3_, A4_); } \
  { const float4 wv_ = *(const float4*)(P1f + (h0_ + 1) * 8); \
    const float bb_  = P1f[(h0_ + 1) * 8 + 4]; \
    float u0_ = fmaf(wv_.x, x, fmaf(wv_.y, f1, fmaf(wv_.z, f2, fmaf(wv_.w, f3, bb_)))); \
    tanh_jets1(u0_, wv_.x, B0_, B1_, B2_, B3_, B4_); } \
  D0 = pkrtz2(A0_, B0_); D1 = pkrtz2(A1_, B1_); D2 = pkrtz2(A2_, B2_); \
  D3 = pkrtz2(A3_, B3_); D4 = pkrtz2(A4_, B4_); }

#define L1HALF(S) { \
  f16x2 qa0, qa1, qa2, qa3, qa4, qb0, qb1, qb2, qb3, qb4; \
  f16x2 qc0, qc1, qc2, qc3, qc4, qd0, qd1, qd2, qd3, qd4; \
  L1P(S, 0, qa0, qa1, qa2, qa3, qa4) \
  L1P(S, 1, qb0, qb1, qb2, qb3, qb4) \
  L1P(S, 2, qc0, qc1, qc2, qc3, qc4) \
  L1P(S, 3, qd0, qd1, qd2, qd3, qd4) \
  bf2[0][S] = cat4(qa0, qb0, qc0, qd0); \
  bf2[1][S] = cat4(qa1, qb1, qc1, qd1); \
  bf2[2][S] = cat4(qa2, qb2, qc2, qd2); \
  bf2[3][S] = cat4(qa3, qb3, qc3, qd3); \
  bf2[4][S] = cat4(qa4, qb4, qc4, qd4); }

// pack half-tile T (rows 0..3) -> packed dwords E (rows 0,1), F (rows 2,3)
#define PKTILE2(T, E0, E1, E2, E3, E4, F0, F1, F2, F3, F4) { \
  float A0_, A1_, A2_, A3_, A4_, B0_, B1_, B2_, B3_, B4_; \
  tanh_jets(acc[0][T][0], acc[1][T][0], acc[2][T][0], acc[3][T][0], acc[4][T][0], \
            A0_, A1_, A2_, A3_, A4_); \
  tanh_jets(acc[0][T][1], acc[1][T][1], acc[2][T][1], acc[3][T][1], acc[4][T][1], \
            B0_, B1_, B2_, B3_, B4_); \
  E0 = pkrtz2(A0_, B0_); E1 = pkrtz2(A1_, B1_); E2 = pkrtz2(A2_, B2_); \
  E3 = pkrtz2(A3_, B3_); E4 = pkrtz2(A4_, B4_); \
  tanh_jets(acc[0][T][2], acc[1][T][2], acc[2][T][2], acc[3][T][2], acc[4][T][2], \
            A0_, A1_, A2_, A3_, A4_); \
  tanh_jets(acc[0][T][3], acc[1][T][3], acc[2][T][3], acc[3][T][3], acc[4][T][3], \
            B0_, B1_, B2_, B3_, B4_); \
  F0 = pkrtz2(A0_, B0_); F1 = pkrtz2(A1_, B1_); F2 = pkrtz2(A2_, B2_); \
  F3 = pkrtz2(A3_, B3_); F4 = pkrtz2(A4_, B4_); }

// pack both half-tiles of this L2 half into bf3[*][HH]
#define PKHALF2(HH) { \
  f16x2 ve0, ve1, ve2, ve3, ve4, vf0, vf1, vf2, vf3, vf4; \
  f16x2 vm0, vm1, vm2, vm3, vm4, vn0, vn1, vn2, vn3, vn4; \
  PKTILE2(0, ve0, ve1, ve2, ve3, ve4, vf0, vf1, vf2, vf3, vf4) \
  PKTILE2(1, vm0, vm1, vm2, vm3, vm4, vn0, vn1, vn2, vn3, vn4) \
  bf3[0][HH] = cat4(ve0, vf0, vm0, vn0); \
  bf3[1][HH] = cat4(ve1, vf1, vm1, vn1); \
  bf3[2][HH] = cat4(ve2, vf2, vm2, vn2); \
  bf3[3][HH] = cat4(ve3, vf3, vm3, vn3); \
  bf3[4][HH] = cat4(ve4, vf4, vm4, vn4); }

// L3 final: half-tile T, global tile TMG -> jets fused into the L4 partials zz
#define L3T(T, TMG) { \
  const float4 wv4_ = *(const float4*)(W4f + 16 * (TMG) + 4 * g); \
  float t0_, t1_, t2_, t3_, t4_; \
  tanh_jets(acc[0][T][0], acc[1][T][0], acc[2][T][0], acc[3][T][0], acc[4][T][0], \
            t0_, t1_, t2_, t3_, t4_); \
  zz[0] = fmaf(wv4_.x, t0_, zz[0]); zz[1] = fmaf(wv4_.x, t1_, zz[1]); \
  zz[2] = fmaf(wv4_.x, t2_, zz[2]); zz[3] = fmaf(wv4_.x, t3_, zz[3]); \
  zz[4] = fmaf(wv4_.x, t4_, zz[4]); \
  tanh_jets(acc[0][T][1], acc[1][T][1], acc[2][T][1], acc[3][T][1], acc[4][T][1], \
            t0_, t1_, t2_, t3_, t4_); \
  zz[0] = fmaf(wv4_.y, t0_, zz[0]); zz[1] = fmaf(wv4_.y, t1_, zz[1]); \
  zz[2] = fmaf(wv4_.y, t2_, zz[2]); zz[3] = fmaf(wv4_.y, t3_, zz[3]); \
  zz[4] = fmaf(wv4_.y, t4_, zz[4]); \
  tanh_jets(acc[0][T][2], acc[1][T][2], acc[2][T][2], acc[3][T][2], acc[4][T][2], \
            t0_, t1_, t2_, t3_, t4_); \
  zz[0] = fmaf(wv4_.z, t0_, zz[0]); zz[1] = fmaf(wv4_.z, t1_, zz[1]); \
  zz[2] = fmaf(wv4_.z, t2_, zz[2]); zz[3] = fmaf(wv4_.z, t3_, zz[3]); \
  zz[4] = fmaf(wv4_.z, t4_, zz[4]); \
  tanh_jets(acc[0][T][3], acc[1][T][3], acc[2][T][3], acc[3][T][3], acc[4][T][3], \
            t0_, t1_, t2_, t3_, t4_); \
  zz[0] = fmaf(wv4_.w, t0_, zz[0]); zz[1] = fmaf(wv4_.w, t1_, zz[1]); \
  zz[2] = fmaf(wv4_.w, t2_, zz[2]); zz[3] = fmaf(wv4_.w, t3_, zz[3]); \
  zz[4] = fmaf(wv4_.w, t4_, zz[4]); }

__global__ __launch_bounds__(64, 4)
void beam_kernel(const float* __restrict__ X, const float* __restrict__ Ein,
                 const float* __restrict__ Iin, const float* __restrict__ Qin,
                 const float* __restrict__ b2, const float* __restrict__ b3,
                 const float* __restrict__ b4, const uint32_t* __restrict__ ws,
                 float* __restrict__ out, int n) {
  const int l   = threadIdx.x & 63;
  const int g   = l >> 4;
  const int p   = l & 15;
  int i = blockIdx.x * 16 + p;      // one wave per workgroup; wave owns 16 points
  if (i >= n) i = n - 1;

  const float x  = X[i];
  const float Ev = Ein[i], Iv = Iin[i], qv = Qin[i];
  const float f1 = Ev * 5.0e-12f;   // E / 2e11
  const float f2 = Iv * 1.0e6f;     // I / 1e-6
  const float f3 = qv * 1.0e-3f;    // q / 1e3
  const float sf = qv * fast_rcp(fmaf(Ev, Iv, 1.1920929e-7f));  // q/(E*I+eps)

  const float* P1f = (const float*)ws;
  const float* W4f = (const float*)(ws + 4608);

  // ---- PREFETCH: issue ALL 16 weight-frag loads up front; their ~200-cyc
  //      L2 latency hides under the ~1200-cyc L1 jet phase. ----
  B128 W2f0, W2f1, W2f2, W2f3, W2f4, W2f5, W2f6, W2f7;
  B128 W3f0, W3f1, W3f2, W3f3, W3f4, W3f5, W3f6, W3f7;
  W2f0.q = *(const u128a*)(ws + 512 + ((0) * 64 + l) * 4);
  W2f1.q = *(const u128a*)(ws + 512 + ((1) * 64 + l) * 4);
  W2f2.q = *(const u128a*)(ws + 512 + ((2) * 64 + l) * 4);
  W2f3.q = *(const u128a*)(ws + 512 + ((3) * 64 + l) * 4);
  W2f4.q = *(const u128a*)(ws + 512 + ((4) * 64 + l) * 4);
  W2f5.q = *(const u128a*)(ws + 512 + ((5) * 64 + l) * 4);
  W2f6.q = *(const u128a*)(ws + 512 + ((6) * 64 + l) * 4);
  W2f7.q = *(const u128a*)(ws + 512 + ((7) * 64 + l) * 4);
  W3f0.q = *(const u128a*)(ws + 2560 + ((0) * 64 + l) * 4);
  W3f1.q = *(const u128a*)(ws + 2560 + ((1) * 64 + l) * 4);
  W3f2.q = *(const u128a*)(ws + 2560 + ((2) * 64 + l) * 4);
  W3f3.q = *(const u128a*)(ws + 2560 + ((3) * 64 + l) * 4);
  W3f4.q = *(const u128a*)(ws + 2560 + ((4) * 64 + l) * 4);
  W3f5.q = *(const u128a*)(ws + 2560 + ((5) * 64 + l) * 4);
  W3f6.q = *(const u128a*)(ws + 2560 + ((6) * 64 + l) * 4);
  W3f7.q = *(const u128a*)(ws + 2560 + ((7) * 64 + l) * 4);

  // ---- Layer 1 (pkrtz pair-packed straight into L2 B-frags) ----
  f16x8 bf2[5][2];
  L1HALF(0)
  L1HALF(1)

  // ---- Layer 2: two half-tile passes (40 acc regs live) ----
  f16x8 bf3[5][2];
  f32x4 acc[5][2];
  {
    INIT2(b2, 0)
    MM5H(W2f0, 0, 0, bf2) MM5H(W2f2, 1, 0, bf2)
    MM5H(W2f1, 0, 1, bf2) MM5H(W2f3, 1, 1, bf2)
    PKHALF2(0)
  }
  {
    INIT2(b2, 1)
    MM5H(W2f4, 0, 0, bf2) MM5H(W2f6, 1, 0, bf2)
    MM5H(W2f5, 0, 1, bf2) MM5H(W2f7, 1, 1, bf2)
    PKHALF2(1)
  }

  // ---- Layer 3 + fused Layer 4: two half-tile passes ----
  float zz[5] = {0.f, 0.f, 0.f, 0.f, 0.f};
  {
    INIT2(b3, 0)
    MM5H(W3f0, 0, 0, bf3) MM5H(W3f2, 1, 0, bf3)
    MM5H(W3f1, 0, 1, bf3) MM5H(W3f3, 1, 1, bf3)
    L3T(0, 0)
    L3T(1, 1)
  }
  {
    INIT2(b3, 1)
    MM5H(W3f4, 0, 0, bf3) MM5H(W3f6, 1, 0, bf3)
    MM5H(W3f5, 0, 1, bf3) MM5H(W3f7, 1, 1, bf3)
    L3T(0, 2)
    L3T(1, 3)
  }

  // ---- butterfly reduce over the 4 lanes sharing point p ----
  #pragma unroll
  for (int k = 0; k < 5; ++k) {
    zz[k] += __shfl_xor(zz[k], 16, 64);
    zz[k] += __shfl_xor(zz[k], 32, 64);
  }

  // All 64 lanes hold the full sums; group g stores row g, row 4 by l<16.
  const float psi   = zz[0] + b4[0];
  const float px    = zz[1];
  const float pxx   = 2.0f  * zz[2];
  const float pxxx  = 6.0f  * zz[3];
  const float pxxxx = 24.0f * zz[4];
  const float x2 = x * x;
  const float o0 = sf * (x2 * psi);
  const float o1 = sf * fmaf(2.0f * x, psi, x2 * px);
  const float o2 = sf * (fmaf(4.0f * x, px, 2.0f * psi) + x2 * pxx);
  const float o3 = sf * (fmaf(6.0f * x, pxx, 6.0f * px) + x2 * pxxx);
  const float o4 = sf * (fmaf(8.0f * x, pxxx, 12.0f * pxx) + x2 * pxxxx);
  const float og = (g == 0) ? o0 : (g == 1) ? o1 : (g == 2) ? o2 : o3;
  out[g * n + i] = og;
  if (l < 16) out[4 * n + i] = o4;
}

extern "C" void kernel_launch(void* const* d_in, const int* in_sizes, int n_in,
                              void* d_out, int out_size, void* d_ws, size_t ws_size,
                              hipStream_t stream) {
  const float* X  = (const float*)d_in[0];
  const float* E  = (const float*)d_in[1];
  const float* I  = (const float*)d_in[2];
  const float* q  = (const float*)d_in[3];
  const float* W1 = (const float*)d_in[4];
  const float* b1 = (const float*)d_in[5];
  const float* W2 = (const float*)d_in[6];
  const float* b2 = (const float*)d_in[7];
  const float* W3 = (const float*)d_in[8];
  const float* b3 = (const float*)d_in[9];
  const float* W4 = (const float*)d_in[10];
  const float* b4 = (const float*)d_in[11];
  const int n = in_sizes[0];
  uint32_t* ws = (uint32_t*)d_ws;
  float* out = (float*)d_out;

  prep_kernel<<<dim3(1), dim3(256), 0, stream>>>(W1, b1, W2, W3, W4, ws);
  // 1-wave workgroups: each wave owns 16 points -> grid = n/16
  beam_kernel<<<dim3((n + 15) / 16), dim3(64), 0, stream>>>(X, E, I, q, b2, b3, b4, ws, out, n);
}

// Round 18
// 53.404 us; speedup vs baseline: 1.2461x; 1.2461x over previous
//
#include <hip/hip_runtime.h>
#include <stdint.h>

typedef _Float16 f16x2 __attribute__((ext_vector_type(2)));
typedef _Float16 f16x4 __attribute__((ext_vector_type(4)));
typedef _Float16 f16x8 __attribute__((ext_vector_type(8)));
typedef __fp16   hf16x2 __attribute__((ext_vector_type(2)));
typedef float    f32x4 __attribute__((ext_vector_type(4)));
typedef uint4    u128a __attribute__((may_alias));

union HU   { uint32_t u; _Float16 h[2]; };
union HF2  { uint32_t u; f16x2 v; };
union B128 { uint4 q; f16x8 v; };
union PK2  { hf16x2 a; f16x2 b; };

__device__ __forceinline__ f16x2 pkrtz2(float lo, float hi) {
  PK2 u; u.a = __builtin_amdgcn_cvt_pkrtz(lo, hi);
  return u.b;
}

__device__ __forceinline__ f16x2 spl(float c) {
  f16x2 v; v[0] = (_Float16)c; v[1] = (_Float16)c; return v;
}

__device__ __forceinline__ f16x8 cat4(f16x2 a, f16x2 b, f16x2 c, f16x2 d) {
  f16x4 ab = __builtin_shufflevector(a, b, 0, 1, 2, 3);
  f16x4 cd = __builtin_shufflevector(c, d, 0, 1, 2, 3);
  return __builtin_shufflevector(ab, cd, 0, 1, 2, 3, 4, 5, 6, 7);
}

__device__ __forceinline__ float fdot2f(f16x2 a, f16x2 b, float c) {
#if __has_builtin(__builtin_amdgcn_fdot2)
  return __builtin_amdgcn_fdot2(a, b, c, false);
#else
  return fmaf((float)a[1], (float)b[1], fmaf((float)a[0], (float)b[0], c));
#endif
}

__device__ __forceinline__ float fast_exp2(float x) {
#if __has_builtin(__builtin_amdgcn_exp2f)
  return __builtin_amdgcn_exp2f(x);
#else
  return exp2f(x);
#endif
}
__device__ __forceinline__ float fast_rcp(float x) {
#if __has_builtin(__builtin_amdgcn_rcpf)
  return __builtin_amdgcn_rcpf(x);
#else
  return 1.0f / x;
#endif
}

// Packed degree-4 tanh jet for a PAIR of units (A,B): t0/v0 in f32, the
// t1..t4 recurrence entirely in packed f16 (v_pk_* ops). Outputs packed.
__device__ __forceinline__ void jets_pk(
    float z0A, float z1A, float z2A, float z3A, float z4A,
    float z0B, float z1B, float z2B, float z3B, float z4B,
    f16x2& T0, f16x2& T1, f16x2& T2, f16x2& T3, f16x2& T4) {
  float aaA = fminf(fmaf(2.8853900817779268f, z0A, 2.0f), 127.0f);
  float aaB = fminf(fmaf(2.8853900817779268f, z0B, 2.0f), 127.0f);
  float e4A = fast_exp2(aaA), e4B = fast_exp2(aaB);
  float rA  = fast_rcp(fmaf(0.25f, e4A, 1.0f));
  float rB  = fast_rcp(fmaf(0.25f, e4B, 1.0f));
  T0 = pkrtz2(fmaf(-2.0f, rA, 1.0f), fmaf(-2.0f, rB, 1.0f));
  f16x2 V0 = pkrtz2(e4A * (rA * rA), e4B * (rB * rB));
  f16x2 U1 = pkrtz2(z1A, z1B);
  f16x2 U2 = pkrtz2(z2A, z2B);
  f16x2 U3 = pkrtz2(z3A, z3B);
  f16x2 U4 = pkrtz2(z4A, z4B);
  T1 = V0 * U1;
  f16x2 h1  = T0 * T1;                       // v1 = -2*h1
  T2 = U2 * V0 - U1 * h1;
  f16x2 v2n = (T0 + T0) * T2 + T1 * T1;      // v2 = -v2n
  T3 = U3 * V0 - spl(1.3333334f) * (U2 * h1) - spl(0.33333334f) * (U1 * v2n);
  f16x2 v3h = T0 * T3 + T1 * T2;             // v3 = -2*v3h
  T4 = U4 * V0 - spl(1.5f) * (U3 * h1) - spl(0.5f) * (U2 * v2n) - spl(0.5f) * (U1 * v3h);
}

// Specialized for layer 1 (z2 = z3 = z4 = 0), pair form.
__device__ __forceinline__ void jets_pk1(
    float z0A, float z1A, float z0B, float z1B,
    f16x2& T0, f16x2& T1, f16x2& T2, f16x2& T3, f16x2& T4) {
  float aaA = fminf(fmaf(2.8853900817779268f, z0A, 2.0f), 127.0f);
  float aaB = fminf(fmaf(2.8853900817779268f, z0B, 2.0f), 127.0f);
  float e4A = fast_exp2(aaA), e4B = fast_exp2(aaB);
  float rA  = fast_rcp(fmaf(0.25f, e4A, 1.0f));
  float rB  = fast_rcp(fmaf(0.25f, e4B, 1.0f));
  T0 = pkrtz2(fmaf(-2.0f, rA, 1.0f), fmaf(-2.0f, rB, 1.0f));
  f16x2 V0 = pkrtz2(e4A * (rA * rA), e4B * (rB * rB));
  f16x2 U1 = pkrtz2(z1A, z1B);
  T1 = V0 * U1;
  f16x2 h1  = T0 * T1;
  T2 = -(U1 * h1);
  f16x2 v2n = (T0 + T0) * T2 + T1 * T1;
  T3 = -spl(0.33333334f) * (U1 * v2n);
  f16x2 v3h = T0 * T3 + T1 * T2;
  T4 = -spl(0.5f) * (U1 * v3h);
}

// ws layout (dwords):
//   [0    .. 511 ]  P1: [h][8] floats = {W1[0][h],W1[1][h],W1[2][h],W1[3][h],b1[h],0,0,0}
//   [512  .. 2559]  W2 A-frags, k2(g,j,s) = 16g + 8s + j          (frag fi = tm*2+s)
//   [2560 .. 4607]  W3 A-frags, k3(g,j,s) = 32s + 16*(j>>2) + 4g + (j&3)
//   [4608 .. 5119]  W4 f16 pairs: [lane l][tm][hf] = (W4[16tm+4g+2hf], W4[16tm+4g+2hf+1])
__global__ void prep_kernel(const float* __restrict__ W1, const float* __restrict__ b1,
                            const float* __restrict__ W2, const float* __restrict__ W3,
                            const float* __restrict__ W4, uint32_t* __restrict__ ws) {
  const int t = threadIdx.x;  // 256 threads, 1 block
  float* P1 = (float*)ws;
  if (t < 64) {
    P1[t * 8 + 0] = W1[0 * 64 + t];
    P1[t * 8 + 1] = W1[1 * 64 + t];
    P1[t * 8 + 2] = W1[2 * 64 + t];
    P1[t * 8 + 3] = W1[3 * 64 + t];
    P1[t * 8 + 4] = b1[t];
    P1[t * 8 + 5] = 0.f; P1[t * 8 + 6] = 0.f; P1[t * 8 + 7] = 0.f;
  }
  for (int idx = t; idx < 2048; idx += 256) {
    const int fi = idx >> 8;            // frag index 0..7 = tm*2 + s
    const int tm = fi >> 1, s = fi & 1;
    const int l  = (idx >> 2) & 63;     // lane
    const int pj = idx & 3;             // dword: halves j0=2pj, j0+1
    const int g  = l >> 4;
    const int mm = 16 * tm + (l & 15);  // h_out row
    const int j0 = 2 * pj, j1 = 2 * pj + 1;
    const int k2a = 16 * g + 8 * s + j0;
    const int k2b = 16 * g + 8 * s + j1;
    HU a; a.h[0] = (_Float16)W2[k2a * 64 + mm]; a.h[1] = (_Float16)W2[k2b * 64 + mm];
    ws[512 + idx] = a.u;
    const int k3a = 32 * s + 16 * (j0 >> 2) + 4 * g + (j0 & 3);
    const int k3b = 32 * s + 16 * (j1 >> 2) + 4 * g + (j1 & 3);
    HU b; b.h[0] = (_Float16)W3[k3a * 64 + mm]; b.h[1] = (_Float16)W3[k3b * 64 + mm];
    ws[2560 + idx] = b.u;
  }
  for (int t2 = t; t2 < 512; t2 += 256) {
    const int lq = t2 >> 3;             // lane
    const int tm = (t2 >> 1) & 3;
    const int hf = t2 & 1;
    const int h0 = 16 * tm + 4 * (lq >> 4) + 2 * hf;
    HU a; a.h[0] = (_Float16)W4[h0]; a.h[1] = (_Float16)W4[h0 + 1];
    ws[4608 + t2] = a.u;
  }
}

#define MFMA16(A, B, C) __builtin_amdgcn_mfma_f32_16x16x32_f16((A), (B), (C), 0, 0, 0)

// One A-frag vs all 5 jet B-frags of half S, accumulating into half-tile T (0/1).
#define MM5H(AF, T, S, BF) { \
    acc[0][T] = MFMA16((AF).v, BF[0][S], acc[0][T]); \
    acc[1][T] = MFMA16((AF).v, BF[1][S], acc[1][T]); \
    acc[2][T] = MFMA16((AF).v, BF[2][S], acc[2][T]); \
    acc[3][T] = MFMA16((AF).v, BF[3][S], acc[3][T]); \
    acc[4][T] = MFMA16((AF).v, BF[4][S], acc[4][T]); }

// init the 2 half-tile accumulators with bias tiles (2*HH, 2*HH+1)
#define INIT2(BIAS, HH) { \
  const float4 bv0_ = *(const float4*)((BIAS) + 16 * (2 * (HH) + 0) + 4 * g); \
  const float4 bv1_ = *(const float4*)((BIAS) + 16 * (2 * (HH) + 1) + 4 * g); \
  acc[0][0] = (f32x4){bv0_.x, bv0_.y, bv0_.z, bv0_.w}; \
  acc[0][1] = (f32x4){bv1_.x, bv1_.y, bv1_.z, bv1_.w}; \
  acc[1][0] = (f32x4){0.f, 0.f, 0.f, 0.f}; acc[1][1] = (f32x4){0.f, 0.f, 0.f, 0.f}; \
  acc[2][0] = (f32x4){0.f, 0.f, 0.f, 0.f}; acc[2][1] = (f32x4){0.f, 0.f, 0.f, 0.f}; \
  acc[3][0] = (f32x4){0.f, 0.f, 0.f, 0.f}; acc[3][1] = (f32x4){0.f, 0.f, 0.f, 0.f}; \
  acc[4][0] = (f32x4){0.f, 0.f, 0.f, 0.f}; acc[4][1] = (f32x4){0.f, 0.f, 0.f, 0.f}; }

// L1: pair (h0, h0+1) of half S, pair-index DI -> 5 packed dwords via jets_pk1
#define L1P(S, DI, D0, D1, D2, D3, D4) { \
  const int h0_ = 16 * g + 8 * (S) + 2 * (DI); \
  const float4 wvA_ = *(const float4*)(P1f + h0_ * 8); \
  const float bbA_  = P1f[h0_ * 8 + 4]; \
  const float u0A_  = fmaf(wvA_.x, x, fmaf(wvA_.y, f1, fmaf(wvA_.z, f2, fmaf(wvA_.w, f3, bbA_)))); \
  const float4 wvB_ = *(const float4*)(P1f + (h0_ + 1) * 8); \
  const float bbB_  = P1f[(h0_ + 1) * 8 + 4]; \
  const float u0B_  = fmaf(wvB_.x, x, fmaf(wvB_.y, f1, fmaf(wvB_.z, f2, fmaf(wvB_.w, f3, bbB_)))); \
  jets_pk1(u0A_, wvA_.x, u0B_, wvB_.x, D0, D1, D2, D3, D4); }

#define L1HALF(S) { \
  f16x2 qa0, qa1, qa2, qa3, qa4, qb0, qb1, qb2, qb3, qb4; \
  f16x2 qc0, qc1, qc2, qc3, qc4, qd0, qd1, qd2, qd3, qd4; \
  L1P(S, 0, qa0, qa1, qa2, qa3, qa4) \
  L1P(S, 1, qb0, qb1, qb2, qb3, qb4) \
  L1P(S, 2, qc0, qc1, qc2, qc3, qc4) \
  L1P(S, 3, qd0, qd1, qd2, qd3, qd4) \
  bf2[0][S] = cat4(qa0, qb0, qc0, qd0); \
  bf2[1][S] = cat4(qa1, qb1, qc1, qd1); \
  bf2[2][S] = cat4(qa2, qb2, qc2, qd2); \
  bf2[3][S] = cat4(qa3, qb3, qc3, qd3); \
  bf2[4][S] = cat4(qa4, qb4, qc4, qd4); }

// pack half-tile T: rows (0,1) -> E*, rows (2,3) -> F*, via packed jets
#define PKTILE2(T, E0, E1, E2, E3, E4, F0, F1, F2, F3, F4) { \
  jets_pk(acc[0][T][0], acc[1][T][0], acc[2][T][0], acc[3][T][0], acc[4][T][0], \
          acc[0][T][1], acc[1][T][1], acc[2][T][1], acc[3][T][1], acc[4][T][1], \
          E0, E1, E2, E3, E4); \
  jets_pk(acc[0][T][2], acc[1][T][2], acc[2][T][2], acc[3][T][2], acc[4][T][2], \
          acc[0][T][3], acc[1][T][3], acc[2][T][3], acc[3][T][3], acc[4][T][3], \
          F0, F1, F2, F3, F4); }

// pack both half-tiles of this L2 half into bf3[*][HH]
#define PKHALF2(HH) { \
  f16x2 ve0, ve1, ve2, ve3, ve4, vf0, vf1, vf2, vf3, vf4; \
  f16x2 vm0, vm1, vm2, vm3, vm4, vn0, vn1, vn2, vn3, vn4; \
  PKTILE2(0, ve0, ve1, ve2, ve3, ve4, vf0, vf1, vf2, vf3, vf4) \
  PKTILE2(1, vm0, vm1, vm2, vm3, vm4, vn0, vn1, vn2, vn3, vn4) \
  bf3[0][HH] = cat4(ve0, vf0, vm0, vn0); \
  bf3[1][HH] = cat4(ve1, vf1, vm1, vn1); \
  bf3[2][HH] = cat4(ve2, vf2, vm2, vn2); \
  bf3[3][HH] = cat4(ve3, vf3, vm3, vn3); \
  bf3[4][HH] = cat4(ve4, vf4, vm4, vn4); }

// L3 final: half-tile T, global tile TMG -> packed jets, fdot2 into zz
#define L3T(T, TMG) { \
  HF2 wa_, wb_; \
  wa_.u = W4p[l * 8 + (TMG) * 2 + 0]; \
  wb_.u = W4p[l * 8 + (TMG) * 2 + 1]; \
  f16x2 t0_, t1_, t2_, t3_, t4_; \
  jets_pk(acc[0][T][0], acc[1][T][0], acc[2][T][0], acc[3][T][0], acc[4][T][0], \
          acc[0][T][1], acc[1][T][1], acc[2][T][1], acc[3][T][1], acc[4][T][1], \
          t0_, t1_, t2_, t3_, t4_); \
  zz[0] = fdot2f(t0_, wa_.v, zz[0]); zz[1] = fdot2f(t1_, wa_.v, zz[1]); \
  zz[2] = fdot2f(t2_, wa_.v, zz[2]); zz[3] = fdot2f(t3_, wa_.v, zz[3]); \
  zz[4] = fdot2f(t4_, wa_.v, zz[4]); \
  jets_pk(acc[0][T][2], acc[1][T][2], acc[2][T][2], acc[3][T][2], acc[4][T][2], \
          acc[0][T][3], acc[1][T][3], acc[2][T][3], acc[3][T][3], acc[4][T][3], \
          t0_, t1_, t2_, t3_, t4_); \
  zz[0] = fdot2f(t0_, wb_.v, zz[0]); zz[1] = fdot2f(t1_, wb_.v, zz[1]); \
  zz[2] = fdot2f(t2_, wb_.v, zz[2]); zz[3] = fdot2f(t3_, wb_.v, zz[3]); \
  zz[4] = fdot2f(t4_, wb_.v, zz[4]); }

__global__ __launch_bounds__(64, 4)
void beam_kernel(const float* __restrict__ X, const float* __restrict__ Ein,
                 const float* __restrict__ Iin, const float* __restrict__ Qin,
                 const float* __restrict__ b2, const float* __restrict__ b3,
                 const float* __restrict__ b4, const uint32_t* __restrict__ ws,
                 float* __restrict__ out, int n) {
  const int l   = threadIdx.x & 63;
  const int g   = l >> 4;
  const int p   = l & 15;
  int i = blockIdx.x * 16 + p;      // one wave per workgroup; wave owns 16 points
  if (i >= n) i = n - 1;

  const float x  = X[i];
  const float Ev = Ein[i], Iv = Iin[i], qv = Qin[i];
  const float f1 = Ev * 5.0e-12f;   // E / 2e11
  const float f2 = Iv * 1.0e6f;     // I / 1e-6
  const float f3 = qv * 1.0e-3f;    // q / 1e3
  const float sf = qv * fast_rcp(fmaf(Ev, Iv, 1.1920929e-7f));  // q/(E*I+eps)

  const float*    P1f = (const float*)ws;
  const uint32_t* W4p = ws + 4608;

  // ---- Layer 1 (packed jets straight into L2 B-frags) ----
  f16x8 bf2[5][2];
  L1HALF(0)
  L1HALF(1)

  // ---- Layer 2: two half-tile passes (40 acc regs live) ----
  f16x8 bf3[5][2];
  f32x4 acc[5][2];
  {
    B128 Fa, Fb, Fc, Fd;                                   // tiles 0,1
    Fa.q = *(const u128a*)(ws + 512 + ((0) * 64 + l) * 4);
    Fb.q = *(const u128a*)(ws + 512 + ((1) * 64 + l) * 4);
    Fc.q = *(const u128a*)(ws + 512 + ((2) * 64 + l) * 4);
    Fd.q = *(const u128a*)(ws + 512 + ((3) * 64 + l) * 4);
    INIT2(b2, 0)
    MM5H(Fa, 0, 0, bf2) MM5H(Fc, 1, 0, bf2)
    MM5H(Fb, 0, 1, bf2) MM5H(Fd, 1, 1, bf2)
    PKHALF2(0)
  }
  {
    B128 Fa, Fb, Fc, Fd;                                   // tiles 2,3
    Fa.q = *(const u128a*)(ws + 512 + ((4) * 64 + l) * 4);
    Fb.q = *(const u128a*)(ws + 512 + ((5) * 64 + l) * 4);
    Fc.q = *(const u128a*)(ws + 512 + ((6) * 64 + l) * 4);
    Fd.q = *(const u128a*)(ws + 512 + ((7) * 64 + l) * 4);
    INIT2(b2, 1)
    MM5H(Fa, 0, 0, bf2) MM5H(Fc, 1, 0, bf2)
    MM5H(Fb, 0, 1, bf2) MM5H(Fd, 1, 1, bf2)
    PKHALF2(1)
  }

  // ---- Layer 3 + fused Layer 4: two half-tile passes ----
  float zz[5] = {0.f, 0.f, 0.f, 0.f, 0.f};
  {
    B128 Fa, Fb, Fc, Fd;
    Fa.q = *(const u128a*)(ws + 2560 + ((0) * 64 + l) * 4);
    Fb.q = *(const u128a*)(ws + 2560 + ((1) * 64 + l) * 4);
    Fc.q = *(const u128a*)(ws + 2560 + ((2) * 64 + l) * 4);
    Fd.q = *(const u128a*)(ws + 2560 + ((3) * 64 + l) * 4);
    INIT2(b3, 0)
    MM5H(Fa, 0, 0, bf3) MM5H(Fc, 1, 0, bf3)
    MM5H(Fb, 0, 1, bf3) MM5H(Fd, 1, 1, bf3)
    L3T(0, 0)
    L3T(1, 1)
  }
  {
    B128 Fa, Fb, Fc, Fd;
    Fa.q = *(const u128a*)(ws + 2560 + ((4) * 64 + l) * 4);
    Fb.q = *(const u128a*)(ws + 2560 + ((5) * 64 + l) * 4);
    Fc.q = *(const u128a*)(ws + 2560 + ((6) * 64 + l) * 4);
    Fd.q = *(const u128a*)(ws + 2560 + ((7) * 64 + l) * 4);
    INIT2(b3, 1)
    MM5H(Fa, 0, 0, bf3) MM5H(Fc, 1, 0, bf3)
    MM5H(Fb, 0, 1, bf3) MM5H(Fd, 1, 1, bf3)
    L3T(0, 2)
    L3T(1, 3)
  }

  // ---- butterfly reduce over the 4 lanes sharing point p ----
  #pragma unroll
  for (int k = 0; k < 5; ++k) {
    zz[k] += __shfl_xor(zz[k], 16, 64);
    zz[k] += __shfl_xor(zz[k], 32, 64);
  }

  // All 64 lanes hold the full sums; group g stores row g, row 4 by l<16.
  const float psi   = zz[0] + b4[0];
  const float px    = zz[1];
  const float pxx   = 2.0f  * zz[2];
  const float pxxx  = 6.0f  * zz[3];
  const float pxxxx = 24.0f * zz[4];
  const float x2 = x * x;
  const float o0 = sf * (x2 * psi);
  const float o1 = sf * fmaf(2.0f * x, psi, x2 * px);
  const float o2 = sf * (fmaf(4.0f * x, px, 2.0f * psi) + x2 * pxx);
  const float o3 = sf * (fmaf(6.0f * x, pxx, 6.0f * px) + x2 * pxxx);
  const float o4 = sf * (fmaf(8.0f * x, pxxx, 12.0f * pxx) + x2 * pxxxx);
  const float og = (g == 0) ? o0 : (g == 1) ? o1 : (g == 2) ? o2 : o3;
  out[g * n + i] = og;
  if (l < 16) out[4 * n + i] = o4;
}

extern "C" void kernel_launch(void* const* d_in, const int* in_sizes, int n_in,
                              void* d_out, int out_size, void* d_ws, size_t ws_size,
                              hipStream_t stream) {
  const float* X  = (const float*)d_in[0];
  const float* E  = (const float*)d_in[1];
  const float* I  = (const float*)d_in[2];
  const float* q  = (const float*)d_in[3];
  const float* W1 = (const float*)d_in[4];
  const float* b1 = (const float*)d_in[5];
  const float* W2 = (const float*)d_in[6];
  const float* b2 = (const float*)d_in[7];
  const float* W3 = (const float*)d_in[8];
  const float* b3 = (const float*)d_in[9];
  const float* W4 = (const float*)d_in[10];
  const float* b4 = (const float*)d_in[11];
  const int n = in_sizes[0];
  uint32_t* ws = (uint32_t*)d_ws;
  float* out = (float*)d_out;

  prep_kernel<<<dim3(1), dim3(256), 0, stream>>>(W1, b1, W2, W3, W4, ws);
  // 1-wave workgroups: each wave owns 16 points -> grid = n/16
  beam_kernel<<<dim3((n + 15) / 16), dim3(64), 0, stream>>>(X, E, I, q, b2, b3, b4, ws, out, n);
}